// Round 9
// baseline (123.271 us; speedup 1.0000x reference)
//
#include <hip/hip_runtime.h>
#include <hip/hip_cooperative_groups.h>

namespace cg = cooperative_groups;

// QuantHotLowRank: out[n][d] = sum_r Uq[ids[n]][r] * Bq[r][d]
// K=200000, R=64, D=1024, N=16384, 4-bit groupwise fake-quant, group=32.
//
// Preferred path: ONE cooperative launch, grid sized from the runtime's own
// occupancy answer (R8's fixed grid=1024 was rejected -> kernel never ran).
//   phase A (strided): quantize B -> split-bf16 Bq^T planes [1024][64] in ws.
//   grid.sync()
//   phase B (strided over 2048 tiles): gather + fp64-quantize A in-register,
//   stage Bq^T slice to LDS, split-bf16 MFMA (hi*hi+hi*lo+lo*hi, ~2^-18),
//   LDS-transposed coalesced nt stores.
// Fallback (coop unsupported or <2 blocks/CU): R7's two-kernel path.
//
// Quant decisions in FP64 to bit-match the numpy-fp64 reference (fp32 flips
// levels at w/scale ~ n+.5 -> absmax 1.06; fp64 -> 0.25 = 1 bf16 ULP floor).

#define R_DIM 64
#define D_DIM 1024
#define N_IDS 16384

#define BM 64          // rows per tile (4 waves x 16)
#define BN 128         // cols per tile
#define NTILES 2048    // (16384/64) * (1024/128)
#define LDS_STRIDE 72  // ushorts per B-LDS row: 64 + 8 pad (kills bank conflicts)
#define OT_STRIDE 132  // floats per out-LDS row: 128 + 4 pad

typedef __attribute__((ext_vector_type(8))) __bf16 bf16x8;
typedef __attribute__((ext_vector_type(4))) float f32x4;

__device__ inline unsigned short f32_to_bf16_rne(float f) {
  union { float f; unsigned int u; } c; c.f = f;
  unsigned int u = c.u;
  u += 0x7fffu + ((u >> 16) & 1u);   // round-to-nearest-even (finite inputs only)
  return (unsigned short)(u >> 16);
}

__device__ inline float bf16_bits_to_f32(unsigned short h) {
  union { unsigned int u; float f; } c; c.u = ((unsigned int)h) << 16;
  return c.f;
}

// fp64 fake-quant matching numpy bit-exactly; w and group-amax a are fp32.
__device__ inline void quant_split(float w, float a, unsigned short* hi, unsigned short* lo) {
  double amax  = fmax((double)a, 1e-8);
  double scale = amax / 7.0;                       // q_max = (1<<(4-1))-1 = 7
  double t     = (double)w / scale;
  double q     = fmin(fmax(rint(t), -7.0), 7.0) * scale;
  float qf = (float)q;
  unsigned short h = f32_to_bf16_rne(qf);
  *hi = h;
  *lo = f32_to_bf16_rne(qf - bf16_bits_to_f32(h));
}

__device__ inline float group_amax32(float w) {
  float a = fabsf(w);
  a = fmaxf(a, __shfl_xor(a, 1));
  a = fmaxf(a, __shfl_xor(a, 2));
  a = fmaxf(a, __shfl_xor(a, 4));
  a = fmaxf(a, __shfl_xor(a, 8));
  a = fmaxf(a, __shfl_xor(a, 16));
  return a;
}

// =================== shared tile body (used by both paths) ==================
// smem layout: bt planes (36KB) overlaid with out-transpose buffer (33KB).
__device__ inline void do_tile(int bx, int tid, int lane, int wave,
                               unsigned short* bt_hi, unsigned short* bt_lo, float* ot,
                               const float* __restrict__ U, const int* __restrict__ ids,
                               const unsigned short* __restrict__ BqT_hi,
                               const unsigned short* __restrict__ BqT_lo,
                               float* __restrict__ out) {
  const int n0 = (bx & 7) * BN;
  const int m0 = (bx >> 3) * BM + wave * 16;
  const int koff  = (lane >> 4) * 8;
  const int nlane = lane & 15;

  // stage Bq^T slice (rows n0..n0+127 = one contiguous 16KB span per plane)
  {
    const uint4* src_hi = (const uint4*)(BqT_hi + (size_t)n0 * R_DIM);
    const uint4* src_lo = (const uint4*)(BqT_lo + (size_t)n0 * R_DIM);
    #pragma unroll
    for (int it = 0; it < 4; ++it) {
      int c = tid + it * 256;              // 16B chunk index, 0..1023
      int row = c >> 3, off = c & 7;
      *(uint4*)&bt_hi[row * LDS_STRIDE + off * 8] = src_hi[c];
      *(uint4*)&bt_lo[row * LDS_STRIDE + off * 8] = src_lo[c];
    }
  }

  // gather + fp64-quantize this wave's 16 A rows, fully in-register.
  // Lane holds elems s*32+koff..+8 of row (lane&15); lanes {l&15 fixed,
  // l>>4 varying} hold one 32-elem quant group -> amax via shfl 16/32.
  const float* urow = U + (size_t)ids[m0 + nlane] * R_DIM;
  bf16x8 afrag_hi[2], afrag_lo[2];
  #pragma unroll
  for (int s = 0; s < 2; ++s) {            // 2 quant groups == 2 MFMA k-steps
    float4 w0 = *(const float4*)(urow + s * 32 + koff);
    float4 w1 = *(const float4*)(urow + s * 32 + koff + 4);
    float wv[8] = {w0.x, w0.y, w0.z, w0.w, w1.x, w1.y, w1.z, w1.w};
    float a = 0.0f;
    #pragma unroll
    for (int j = 0; j < 8; ++j) a = fmaxf(a, fabsf(wv[j]));
    a = fmaxf(a, __shfl_xor(a, 16));
    a = fmaxf(a, __shfl_xor(a, 32));
    union { unsigned short s8[8]; bf16x8 b; } uh, ul;
    #pragma unroll
    for (int j = 0; j < 8; ++j) {
      unsigned short hi, lo;
      quant_split(wv[j], a, &hi, &lo);
      uh.s8[j] = hi;
      ul.s8[j] = lo;
    }
    afrag_hi[s] = uh.b;
    afrag_lo[s] = ul.b;
  }

  __syncthreads();

  // MFMA: 8 n-frags x 2 k-steps x {hi*hi, hi*lo, lo*hi}
  f32x4 acc[8];
  #pragma unroll
  for (int nf = 0; nf < 8; ++nf) acc[nf] = (f32x4){0.f, 0.f, 0.f, 0.f};
  #pragma unroll
  for (int nf = 0; nf < 8; ++nf) {
    #pragma unroll
    for (int s = 0; s < 2; ++s) {
      const int boff = (nf * 16 + nlane) * LDS_STRIDE + s * 32 + koff;
      union { uint4 u; bf16x8 b; } bh, bl;
      bh.u = *(const uint4*)&bt_hi[boff];
      bl.u = *(const uint4*)&bt_lo[boff];
      acc[nf] = __builtin_amdgcn_mfma_f32_16x16x32_bf16(afrag_hi[s], bh.b, acc[nf], 0, 0, 0);
      acc[nf] = __builtin_amdgcn_mfma_f32_16x16x32_bf16(afrag_hi[s], bl.b, acc[nf], 0, 0, 0);
      acc[nf] = __builtin_amdgcn_mfma_f32_16x16x32_bf16(afrag_lo[s], bh.b, acc[nf], 0, 0, 0);
    }
  }

  __syncthreads();   // done reading B tiles; reuse smem for out-transpose

  float* w = ot + wave * 16 * OT_STRIDE;
  {
    const int r0 = (lane >> 4) << 2;         // 0,4,8,12
    #pragma unroll
    for (int nf = 0; nf < 8; ++nf) {
      #pragma unroll
      for (int i = 0; i < 4; ++i) {
        w[(r0 + i) * OT_STRIDE + nlane + nf * 16] = acc[nf][i];
      }
    }
  }
  #pragma unroll
  for (int j = 0; j < 8; ++j) {
    const int row = j * 2 + (lane >> 5);     // 0..15
    f32x4 v = *(const f32x4*)&w[row * OT_STRIDE + (lane & 31) * 4];
    // 32 lanes x 16B = one contiguous 512B row segment; nt write-once stream
    __builtin_nontemporal_store(v,
        (f32x4*)&out[(size_t)(m0 + row) * D_DIM + n0 + (lane & 31) * 4]);
  }
}

// ====================== path 1: cooperative fused kernel ====================
__global__ __launch_bounds__(256, 4) void coop_kernel(
    const float* __restrict__ U, const float* __restrict__ B,
    const int* __restrict__ ids,
    unsigned short* __restrict__ BqT_hi, unsigned short* __restrict__ BqT_lo,
    float* __restrict__ out) {
  __shared__ char smem[2 * BN * LDS_STRIDE * 2];   // 36864B
  unsigned short* bt_hi = (unsigned short*)smem;
  unsigned short* bt_lo = bt_hi + BN * LDS_STRIDE;
  float* ot = (float*)smem;

  const int tid  = threadIdx.x;
  const int lane = tid & 63;
  const int wave = tid >> 6;
  const int grid = gridDim.x;

  // phase A: quantize B (strided; wave-aligned so shuffle groups are intact)
  for (int e0 = blockIdx.x * 256; e0 < R_DIM * D_DIM; e0 += grid * 256) {
    int e = e0 + tid;
    int r = e >> 10;
    int c = e & 1023;
    float w = B[e];
    unsigned short hi, lo;
    quant_split(w, group_amax32(w), &hi, &lo);
    BqT_hi[c * R_DIM + r] = hi;
    BqT_lo[c * R_DIM + r] = lo;
  }
  __threadfence();
  cg::this_grid().sync();

  // phase B: persistent loop over output tiles
  for (int bx = blockIdx.x; bx < NTILES; bx += grid) {
    __syncthreads();   // prior iteration's LDS reads complete before restage
    do_tile(bx, tid, lane, wave, bt_hi, bt_lo, ot, U, ids, BqT_hi, BqT_lo, out);
  }
}

// ====================== path 2: fallback two-kernel (R7) ====================
__global__ __launch_bounds__(256) void quantB_kernel(
    const float* __restrict__ B,
    unsigned short* __restrict__ BqT_hi, unsigned short* __restrict__ BqT_lo) {
  int e = blockIdx.x * 256 + threadIdx.x;
  int r = e >> 10;
  int c = e & 1023;
  float w = B[e];
  unsigned short hi, lo;
  quant_split(w, group_amax32(w), &hi, &lo);
  BqT_hi[c * R_DIM + r] = hi;
  BqT_lo[c * R_DIM + r] = lo;
}

__global__ __launch_bounds__(256) void gemm_kernel(
    const float* __restrict__ U, const int* __restrict__ ids,
    const unsigned short* __restrict__ BqT_hi, const unsigned short* __restrict__ BqT_lo,
    float* __restrict__ out) {
  __shared__ char smem[2 * BN * LDS_STRIDE * 2];
  unsigned short* bt_hi = (unsigned short*)smem;
  unsigned short* bt_lo = bt_hi + BN * LDS_STRIDE;
  float* ot = (float*)smem;
  do_tile(blockIdx.x, threadIdx.x, threadIdx.x & 63, threadIdx.x >> 6,
          bt_hi, bt_lo, ot, U, ids, BqT_hi, BqT_lo, out);
}

extern "C" void kernel_launch(void* const* d_in, const int* in_sizes, int n_in,
                              void* d_out, int out_size, void* d_ws, size_t ws_size,
                              hipStream_t stream) {
  const float* U   = (const float*)d_in[0];
  const float* B   = (const float*)d_in[1];
  const int*   ids = (const int*)d_in[2];
  float* out = (float*)d_out;

  unsigned short* BqT_hi = (unsigned short*)d_ws;                       // 128 KB
  unsigned short* BqT_lo = BqT_hi + R_DIM * D_DIM;                      // 128 KB

  // Host-side queries: capture-safe (not stream ops), deterministic, and
  // host cost is outside the timed graph replays.
  int dev = 0;
  (void)hipGetDevice(&dev);
  int coop = 0, ncu = 0, maxb = 0;
  (void)hipDeviceGetAttribute(&coop, hipDeviceAttributeCooperativeLaunch, dev);
  (void)hipDeviceGetAttribute(&ncu, hipDeviceAttributeMultiprocessorCount, dev);
  (void)hipOccupancyMaxActiveBlocksPerMultiprocessor(
      &maxb, (const void*)coop_kernel, 256, 0);

  int grid = maxb * ncu;
  if (grid > NTILES) grid = NTILES;

  if (coop && maxb >= 2 && grid >= 64) {
    void* args[] = {(void*)&U, (void*)&B, (void*)&ids,
                    (void*)&BqT_hi, (void*)&BqT_lo, (void*)&out};
    (void)hipLaunchCooperativeKernel((const void*)coop_kernel, dim3(grid),
                                     dim3(256), args, 0, stream);
  } else {
    quantB_kernel<<<(R_DIM * D_DIM) / 256, 256, 0, stream>>>(B, BqT_hi, BqT_lo);
    gemm_kernel<<<NTILES, 256, 0, stream>>>(U, ids, BqT_hi, BqT_lo, out);
  }
}

// Round 10
// 27.474 us; speedup vs baseline: 4.4868x; 4.4868x over previous
//
#include <hip/hip_runtime.h>

// QuantHotLowRank: out[n][d] = sum_r Uq[ids[n]][r] * Bq[r][d]
// K=200000, R=64, D=1024, N=16384, 4-bit groupwise fake-quant, group=32.
//
// Two kernels (cooperative single-launch measured 5.7x WORSE in R9 -- grid
// sync on gfx950 costs far more than the launch gap it saves; reverted):
//   1) quantB: B [64,1024] -> split-bf16 Bq^T planes [1024][64] (hi,lo) in ws.
//   2) gemm:   BM=128 x BN=128 tiles (1024 blocks, 4 waves, 2 m-frags/wave):
//              gather + fp64-quantize A rows in-register, B tile LDS-staged,
//              split-bf16 MFMA (hi*hi + hi*lo + lo*hi, exact to ~2^-18),
//              LDS-transposed coalesced nt stores.
//
// Quant decisions in FP64 to bit-match the numpy-fp64 reference (fp32 flips
// levels at w/scale ~ n+.5 -> absmax 1.06; fp64 -> 0.25 = 1 bf16 ULP floor).

#define R_DIM 64
#define D_DIM 1024
#define N_IDS 16384

#define BM 128         // rows per tile (4 waves x 2 m-frags x 16)
#define BN 128         // cols per tile
#define LDS_STRIDE 72  // ushorts per B-LDS row: 64 + 8 pad (kills bank conflicts)
#define OT_STRIDE 132  // floats per out-LDS row: 128 + 4 pad

typedef __attribute__((ext_vector_type(8))) __bf16 bf16x8;
typedef __attribute__((ext_vector_type(4))) float f32x4;

__device__ inline unsigned short f32_to_bf16_rne(float f) {
  union { float f; unsigned int u; } c; c.f = f;
  unsigned int u = c.u;
  u += 0x7fffu + ((u >> 16) & 1u);   // round-to-nearest-even (finite inputs only)
  return (unsigned short)(u >> 16);
}

__device__ inline float bf16_bits_to_f32(unsigned short h) {
  union { unsigned int u; float f; } c; c.u = ((unsigned int)h) << 16;
  return c.f;
}

// fp64 fake-quant of one element given the group's fp64 scale (= amax/7,
// hoisted -- identical bits to recomputing per element).
__device__ inline void quant_elem(float w, double scale,
                                  unsigned short* hi, unsigned short* lo) {
  double t = (double)w / scale;                    // exact IEEE fp64 div = np
  double q = fmin(fmax(rint(t), -7.0), 7.0) * scale;
  float qf = (float)q;
  unsigned short h = f32_to_bf16_rne(qf);
  *hi = h;
  *lo = f32_to_bf16_rne(qf - bf16_bits_to_f32(h));
}

// ---------------- Kernel 1: quantize B -> split Bq^T (bf16 hi/lo planes) ----
// 64 blocks x 256 threads x 4 elems (float4); group of 32 = 8 consecutive
// lanes' float4s (aligned since 256 % 8 == 0).
__global__ __launch_bounds__(256) void quantB_kernel(
    const float* __restrict__ B,
    unsigned short* __restrict__ BqT_hi, unsigned short* __restrict__ BqT_lo) {
  int e4 = blockIdx.x * 256 + threadIdx.x;   // 0..16383
  int e  = e4 * 4;
  int r  = e >> 10;                          // row in [0,64)
  int c  = e & 1023;                         // col in [0,1024), 4 consecutive
  float4 w = *(const float4*)(B + e);
  float a = fmaxf(fmaxf(fabsf(w.x), fabsf(w.y)), fmaxf(fabsf(w.z), fabsf(w.w)));
  a = fmaxf(a, __shfl_xor(a, 1));
  a = fmaxf(a, __shfl_xor(a, 2));
  a = fmaxf(a, __shfl_xor(a, 4));
  double sc = fmax((double)a, 1e-8) / 7.0;
  float wv[4] = {w.x, w.y, w.z, w.w};
  #pragma unroll
  for (int j = 0; j < 4; ++j) {
    unsigned short hi, lo;
    quant_elem(wv[j], sc, &hi, &lo);
    BqT_hi[(c + j) * R_DIM + r] = hi;
    BqT_lo[(c + j) * R_DIM + r] = lo;
  }
}

// ---------------- Kernel 2: 128x128 tile, in-register A-quant, MFMA ---------
__global__ __launch_bounds__(256, 4) void gemm_kernel(
    const float* __restrict__ U, const int* __restrict__ ids,
    const unsigned short* __restrict__ BqT_hi, const unsigned short* __restrict__ BqT_lo,
    float* __restrict__ out) {
  // B tiles (2 planes, 18KB each); reused as the fp32 out-transpose buffer
  // (33KB) in the store phase. 36864B -> 4 blocks/CU (grid 1024 co-resident).
  __shared__ char smem[2 * BN * LDS_STRIDE * 2];
  unsigned short* bt_hi = (unsigned short*)smem;
  unsigned short* bt_lo = bt_hi + BN * LDS_STRIDE;
  float* ot = (float*)smem;

  const int tid  = threadIdx.x;
  const int lane = tid & 63;
  const int wave = tid >> 6;
  const int bx   = blockIdx.x;
  const int nb   = bx & 7;     // 8 col-blocks (== XCD id under %8 round-robin)
  const int mb   = bx >> 3;    // 128 row-blocks
  const int n0   = nb * BN;
  const int m0b  = mb * BM;
  const int koff  = (lane >> 4) * 8;         // k-chunk of 8 within the 32-group
  const int nlane = lane & 15;

  // --- A gather loads FIRST (pure reg loads; fly under B-stage latency) ---
  // m-frag mf covers rows m0b + mf*64 + wave*16 .. +16.
  const float* urow0 = U + (size_t)ids[m0b + wave * 16 + nlane] * R_DIM;
  const float* urow1 = U + (size_t)ids[m0b + 64 + wave * 16 + nlane] * R_DIM;
  float4 wr[2][2][2];
  #pragma unroll
  for (int s = 0; s < 2; ++s) {
    wr[0][s][0] = *(const float4*)(urow0 + s * 32 + koff);
    wr[0][s][1] = *(const float4*)(urow0 + s * 32 + koff + 4);
    wr[1][s][0] = *(const float4*)(urow1 + s * 32 + koff);
    wr[1][s][1] = *(const float4*)(urow1 + s * 32 + koff + 4);
  }

  // --- stage Bq^T slice (rows n0..n0+127 = one contiguous 16KB span/plane) --
  {
    const uint4* src_hi = (const uint4*)(BqT_hi + (size_t)n0 * R_DIM);
    const uint4* src_lo = (const uint4*)(BqT_lo + (size_t)n0 * R_DIM);
    #pragma unroll
    for (int it = 0; it < 4; ++it) {
      int c = tid + it * 256;                // 16B chunk index, 0..1023
      int row = c >> 3, off = c & 7;
      *(uint4*)&bt_hi[row * LDS_STRIDE + off * 8] = src_hi[c];
      *(uint4*)&bt_lo[row * LDS_STRIDE + off * 8] = src_lo[c];
    }
  }

  // --- fp64-quantize A fragments in-register (overlaps stage latency) ------
  // Lane holds elems s*32+koff..+8 of its row; lanes {l&15 fixed, l>>4
  // varying} hold one 32-elem quant group -> amax via shfl_xor 16/32.
  bf16x8 ah[2][2], al[2][2];
  #pragma unroll
  for (int mf = 0; mf < 2; ++mf) {
    #pragma unroll
    for (int s = 0; s < 2; ++s) {
      float4 w0 = wr[mf][s][0], w1 = wr[mf][s][1];
      float wv[8] = {w0.x, w0.y, w0.z, w0.w, w1.x, w1.y, w1.z, w1.w};
      float a = 0.0f;
      #pragma unroll
      for (int j = 0; j < 8; ++j) a = fmaxf(a, fabsf(wv[j]));
      a = fmaxf(a, __shfl_xor(a, 16));
      a = fmaxf(a, __shfl_xor(a, 32));
      double sc = fmax((double)a, 1e-8) / 7.0;
      union { unsigned short s8[8]; bf16x8 b; } uh, ul;
      #pragma unroll
      for (int j = 0; j < 8; ++j) {
        unsigned short hi, lo;
        quant_elem(wv[j], sc, &hi, &lo);
        uh.s8[j] = hi;
        ul.s8[j] = lo;
      }
      ah[mf][s] = uh.b;
      al[mf][s] = ul.b;
    }
  }

  __syncthreads();

  // --- MFMA: 8 n-frags x 2 k-steps x 2 m-frags x {hi*hi, hi*lo, lo*hi} -----
  // One bh/bl LDS read pair now feeds 6 MFMAs (2x better amortized than R7).
  f32x4 acc[2][8];
  #pragma unroll
  for (int mf = 0; mf < 2; ++mf)
    #pragma unroll
    for (int nf = 0; nf < 8; ++nf) acc[mf][nf] = (f32x4){0.f, 0.f, 0.f, 0.f};

  #pragma unroll
  for (int nf = 0; nf < 8; ++nf) {
    #pragma unroll
    for (int s = 0; s < 2; ++s) {
      const int boff = (nf * 16 + nlane) * LDS_STRIDE + s * 32 + koff;
      union { uint4 u; bf16x8 b; } bh, bl;
      bh.u = *(const uint4*)&bt_hi[boff];
      bl.u = *(const uint4*)&bt_lo[boff];
      #pragma unroll
      for (int mf = 0; mf < 2; ++mf) {
        acc[mf][nf] = __builtin_amdgcn_mfma_f32_16x16x32_bf16(ah[mf][s], bh.b, acc[mf][nf], 0, 0, 0);
        acc[mf][nf] = __builtin_amdgcn_mfma_f32_16x16x32_bf16(ah[mf][s], bl.b, acc[mf][nf], 0, 0, 0);
        acc[mf][nf] = __builtin_amdgcn_mfma_f32_16x16x32_bf16(al[mf][s], bh.b, acc[mf][nf], 0, 0, 0);
      }
    }
  }

  __syncthreads();   // done reading B tiles; reuse smem for out-transpose

  // --- per-wave LDS transpose + coalesced nt stores, one round per m-frag ---
  // Each wave owns its private ot region; round 2 reuses it (same-wave
  // LDS ordering handled by compiler-inserted lgkmcnt).
  float* wp = ot + wave * 16 * OT_STRIDE;
  #pragma unroll
  for (int mf = 0; mf < 2; ++mf) {
    const int r0 = (lane >> 4) << 2;         // 0,4,8,12
    #pragma unroll
    for (int nf = 0; nf < 8; ++nf) {
      #pragma unroll
      for (int i = 0; i < 4; ++i) {
        wp[(r0 + i) * OT_STRIDE + nlane + nf * 16] = acc[mf][nf][i];
      }
    }
    const int orow0 = m0b + mf * 64 + wave * 16;
    #pragma unroll
    for (int j = 0; j < 8; ++j) {
      const int row = j * 2 + (lane >> 5);   // 0..15
      f32x4 v = *(const f32x4*)&wp[row * OT_STRIDE + (lane & 31) * 4];
      // 32 lanes x 16B = one contiguous 512B row segment; nt write-once stream
      __builtin_nontemporal_store(v,
          (f32x4*)&out[(size_t)(orow0 + row) * D_DIM + n0 + (lane & 31) * 4]);
    }
  }
}

extern "C" void kernel_launch(void* const* d_in, const int* in_sizes, int n_in,
                              void* d_out, int out_size, void* d_ws, size_t ws_size,
                              hipStream_t stream) {
  const float* U   = (const float*)d_in[0];
  const float* B   = (const float*)d_in[1];
  const int*   ids = (const int*)d_in[2];
  float* out = (float*)d_out;

  unsigned short* BqT_hi = (unsigned short*)d_ws;                       // 128 KB
  unsigned short* BqT_lo = BqT_hi + R_DIM * D_DIM;                      // 128 KB

  quantB_kernel<<<(R_DIM * D_DIM) / (256 * 4), 256, 0, stream>>>(B, BqT_hi, BqT_lo);
  gemm_kernel<<<(N_IDS / BM) * (D_DIM / BN), 256, 0, stream>>>(U, ids, BqT_hi, BqT_lo, out);
}